// Round 1
// baseline (689.850 us; speedup 1.0000x reference)
//
#include <hip/hip_runtime.h>
#include <hip/hip_bf16.h>
#include <math.h>

#define B_ 2
#define TX_ 1024
#define TY_ 4096
#define C_ 768
#define H_ 12
#define D_ 64
#define NSPLIT 4

// ---------------------------------------------------------------------------
// GEMM: out = A(M,768) @ W(768,N), f32, 64x64 tile, BK=16, 4x4 micro-tile.
// MODE 0: plain store to out0 (N==C_)
// MODE 1: rope(pos=t_arr[row]) * 0.125 -> out0   (Q path, N==C_)
// MODE 2: col<C_: rope -> out0 (K); col>=C_: -> out1 (V)   (N==2*C_)
// ---------------------------------------------------------------------------
template<int MODE>
__global__ __launch_bounds__(256)
void gemm_rope(const float* __restrict__ A,
               const float* __restrict__ W,
               float* __restrict__ out0,
               float* __restrict__ out1,
               const float* __restrict__ t_arr,
               const float* __restrict__ inv_freq,
               int N)
{
    const int K = C_;
    __shared__ float As[16][64];
    __shared__ float Bs[16][64];
    const int tx = threadIdx.x, ty = threadIdx.y;
    const int tid = ty * 16 + tx;
    const int row0 = blockIdx.y * 64;
    const int n0   = blockIdx.x * 64;

    float c[4][4];
#pragma unroll
    for (int i = 0; i < 4; i++)
#pragma unroll
        for (int j = 0; j < 4; j++) c[i][j] = 0.f;

    const int aRow = tid >> 2;          // 0..63
    const int aK4  = (tid & 3) * 4;     // 0,4,8,12
    const int bK   = tid >> 4;          // 0..15
    const int bN4  = (tid & 15) * 4;    // 0..60

    for (int k0 = 0; k0 < K; k0 += 16) {
        float4 av = *(const float4*)(A + (size_t)(row0 + aRow) * K + k0 + aK4);
        float4 bv = *(const float4*)(W + (size_t)(k0 + bK) * N + n0 + bN4);
        __syncthreads();
        As[aK4 + 0][aRow] = av.x;
        As[aK4 + 1][aRow] = av.y;
        As[aK4 + 2][aRow] = av.z;
        As[aK4 + 3][aRow] = av.w;
        *(float4*)&Bs[bK][bN4] = bv;
        __syncthreads();
#pragma unroll
        for (int kk = 0; kk < 16; kk++) {
            float4 a4 = *(const float4*)&As[kk][ty * 4];
            float4 b4 = *(const float4*)&Bs[kk][tx * 4];
            float aa[4] = {a4.x, a4.y, a4.z, a4.w};
            float bb[4] = {b4.x, b4.y, b4.z, b4.w};
#pragma unroll
            for (int i = 0; i < 4; i++)
#pragma unroll
                for (int j = 0; j < 4; j++) c[i][j] += aa[i] * bb[j];
        }
    }

    // epilogue
#pragma unroll
    for (int i = 0; i < 4; i++) {
        const int g = row0 + ty * 4 + i;
        if (MODE == 0) {
#pragma unroll
            for (int j = 0; j < 4; j++)
                out0[(size_t)g * C_ + n0 + tx * 4 + j] = c[i][j];
        } else {
            const float pos = t_arr[g];
#pragma unroll
            for (int jp = 0; jp < 2; jp++) {
                const int cn = n0 + tx * 4 + jp * 2;
                float v0 = c[i][jp * 2], v1 = c[i][jp * 2 + 1];
                const bool isK = (MODE == 1) || (cn < C_);
                if (isK) {
                    const int cc = cn & (D_ - 1);
                    const float fr = pos * inv_freq[cc >> 1];
                    float sn, cs;
                    sincosf(fr, &sn, &cs);
                    float r0 = v0 * cs - v1 * sn;
                    float r1 = v1 * cs + v0 * sn;
                    if (MODE == 1) { r0 *= 0.125f; r1 *= 0.125f; }
                    out0[(size_t)g * C_ + cn]     = r0;
                    out0[(size_t)g * C_ + cn + 1] = r1;
                } else {
                    out1[(size_t)g * C_ + (cn - C_)]     = v0;
                    out1[(size_t)g * C_ + (cn - C_ + 1)] = v1;
                }
            }
        }
    }
}

// ---------------------------------------------------------------------------
// Attention: one thread per q row; contiguous valid-k window via binary
// search; block = 64 threads (one wave) = 64 q rows; k-window union split
// NSPLIT ways over blockIdx.z (flash-decoding style), combined later.
// ---------------------------------------------------------------------------
__global__ __launch_bounds__(64)
void attn_kernel(const float* __restrict__ Q,
                 const float* __restrict__ Kr,
                 const float* __restrict__ V,
                 const float* __restrict__ x_t,
                 const float* __restrict__ y_t,
                 const int* __restrict__ dist_p,
                 const int* __restrict__ min_dist_p,
                 float* __restrict__ pacc,
                 float* __restrict__ pml)
{
    const int lane  = threadIdx.x;
    const int qt    = blockIdx.x;   // q tile
    const int bh    = blockIdx.y;   // b*H + h
    const int split = blockIdx.z;
    const int b = bh / H_, h = bh % H_;
    const int txg = qt * 64 + lane;

    const float dist = (float)dist_p[0];
    const float xt   = x_t[b * TX_ + txg] - (float)min_dist_p[0];
    const float* yt  = y_t + (size_t)b * TY_;

    // klo: first k with !(yt[k] + dist < xt)  == (xt <= yt[k]+dist)
    int lo = 0, hi = TY_;
    while (lo < hi) { int mid = (lo + hi) >> 1; if (yt[mid] + dist < xt) lo = mid + 1; else hi = mid; }
    const int klo = lo;
    // khi: last k with yt[k] <= xt
    lo = 0; hi = TY_;
    while (lo < hi) { int mid = (lo + hi) >> 1; if (yt[mid] <= xt) lo = mid + 1; else hi = mid; }
    const int khi = lo - 1;

    int kmin = klo, kmax = khi;
#pragma unroll
    for (int off = 32; off; off >>= 1) {
        kmin = min(kmin, __shfl_xor(kmin, off, 64));
        kmax = max(kmax, __shfl_xor(kmax, off, 64));
    }
    const int len   = kmax - kmin + 1;
    const int chunk = (len + NSPLIT - 1) / NSPLIT;
    const int k0    = kmin + split * chunk;
    const int k1    = min(k0 + chunk, kmax + 1);

    float q[64];
    const float* qp = Q + (size_t)(b * TX_ + txg) * C_ + h * D_;
#pragma unroll
    for (int d = 0; d < 64; d += 4) {
        float4 t = *(const float4*)(qp + d);
        q[d] = t.x; q[d + 1] = t.y; q[d + 2] = t.z; q[d + 3] = t.w;
    }

    float m = -INFINITY, lsum = 0.f;
    float acc[64];
#pragma unroll
    for (int d = 0; d < 64; d++) acc[d] = 0.f;

    __shared__ float Ks[64];
    __shared__ float Vs[64];

    for (int k = k0; k < k1; ++k) {
        __syncthreads();
        const size_t kb = (size_t)(b * TY_ + k) * C_ + h * D_;
        Ks[lane] = Kr[kb + lane];
        Vs[lane] = V[kb + lane];
        __syncthreads();
        if (k >= klo && k <= khi) {
            float s0 = 0.f, s1 = 0.f, s2 = 0.f, s3 = 0.f;
#pragma unroll
            for (int d = 0; d < 64; d += 4) {
                s0 += q[d] * Ks[d];
                s1 += q[d + 1] * Ks[d + 1];
                s2 += q[d + 2] * Ks[d + 2];
                s3 += q[d + 3] * Ks[d + 3];
            }
            const float s  = (s0 + s1) + (s2 + s3);
            const float mn = fmaxf(m, s);
            const float corr = __expf(m - mn);
            const float p    = __expf(s - mn);
            lsum = lsum * corr + p;
#pragma unroll
            for (int d = 0; d < 64; d++) acc[d] = acc[d] * corr + p * Vs[d];
            m = mn;
        }
    }

    const size_t R = (size_t)B_ * H_ * TX_;
    const size_t r = (size_t)bh * TX_ + txg;
    float* pa = pacc + ((size_t)split * R + r) * 64;
#pragma unroll
    for (int d = 0; d < 64; d++) pa[d] = acc[d];
    pml[((size_t)split * R + r) * 2 + 0] = m;
    pml[((size_t)split * R + r) * 2 + 1] = lsum;
}

// ---------------------------------------------------------------------------
// Combine NSPLIT partial online-softmax states -> O (B,TX,C)
// ---------------------------------------------------------------------------
__global__ __launch_bounds__(256)
void combine_kernel(const float* __restrict__ pacc,
                    const float* __restrict__ pml,
                    float* __restrict__ O)
{
    const int d   = threadIdx.x;            // 0..63
    const int sub = threadIdx.y;            // 0..3
    const size_t R = (size_t)B_ * H_ * TX_;
    const size_t r = (size_t)blockIdx.x * 4 + sub;
    const int bh  = (int)(r / TX_);
    const int txg = (int)(r % TX_);
    const int b = bh / H_, h = bh % H_;

    float mv[NSPLIT], lv[NSPLIT];
    float M = -INFINITY;
#pragma unroll
    for (int s = 0; s < NSPLIT; s++) {
        mv[s] = pml[((size_t)s * R + r) * 2 + 0];
        lv[s] = pml[((size_t)s * R + r) * 2 + 1];
        if (lv[s] > 0.f) M = fmaxf(M, mv[s]);
    }
    float L = 0.f, val = 0.f;
#pragma unroll
    for (int s = 0; s < NSPLIT; s++) {
        if (lv[s] > 0.f) {
            const float w = __expf(mv[s] - M);
            L += lv[s] * w;
            val += pacc[((size_t)s * R + r) * 64 + d] * w;
        }
    }
    const float o = (L > 0.f) ? val / L : 0.f;
    O[(size_t)(b * TX_ + txg) * C_ + h * D_ + d] = o;
}

// ---------------------------------------------------------------------------
extern "C" void kernel_launch(void* const* d_in, const int* in_sizes, int n_in,
                              void* d_out, int out_size, void* d_ws, size_t ws_size,
                              hipStream_t stream)
{
    const float* x        = (const float*)d_in[0];
    const float* x_t      = (const float*)d_in[1];
    const float* y        = (const float*)d_in[2];
    const float* y_t      = (const float*)d_in[3];
    const int*   dist     = (const int*)d_in[4];
    const int*   min_dist = (const int*)d_in[5];
    const float* Wq       = (const float*)d_in[6];
    const float* Wkv      = (const float*)d_in[7];
    const float* Wproj    = (const float*)d_in[8];
    const float* inv_freq = (const float*)d_in[9];
    float* out = (float*)d_out;

    float* ws = (float*)d_ws;
    const size_t QN = (size_t)B_ * TX_ * C_;   // 1.57M
    const size_t KN = (size_t)B_ * TY_ * C_;   // 6.29M
    const size_t R  = (size_t)B_ * H_ * TX_;   // 24576
    float* Qb   = ws; ws += QN;
    float* Kb   = ws; ws += KN;
    float* Vb   = ws; ws += KN;
    float* Ob   = ws; ws += QN;
    float* pacc = ws; ws += (size_t)NSPLIT * R * 64;
    float* pml  = ws; ws += (size_t)NSPLIT * R * 2;

    dim3 blk(16, 16);
    // Q = rope(x @ Wq) * 0.125
    gemm_rope<1><<<dim3(C_ / 64, (B_ * TX_) / 64), blk, 0, stream>>>(
        x, Wq, Qb, nullptr, x_t, inv_freq, C_);
    // K = rope(y @ Wkv[:, :C]), V = y @ Wkv[:, C:]
    gemm_rope<2><<<dim3((2 * C_) / 64, (B_ * TY_) / 64), blk, 0, stream>>>(
        y, Wkv, Kb, Vb, y_t, inv_freq, 2 * C_);
    // masked flash attention, k-split
    attn_kernel<<<dim3(TX_ / 64, B_ * H_, NSPLIT), dim3(64), 0, stream>>>(
        Qb, Kb, Vb, x_t, y_t, dist, min_dist, pacc, pml);
    // combine partials -> O
    combine_kernel<<<dim3((unsigned)(R / 4)), dim3(64, 4), 0, stream>>>(
        pacc, pml, Ob);
    // out = O @ Wproj
    gemm_rope<0><<<dim3(C_ / 64, (B_ * TX_) / 64), blk, 0, stream>>>(
        Ob, Wproj, out, nullptr, nullptr, nullptr, C_);
}

// Round 2
// 566.069 us; speedup vs baseline: 1.2187x; 1.2187x over previous
//
#include <hip/hip_runtime.h>
#include <hip/hip_bf16.h>
#include <math.h>

#define B_ 2
#define TX_ 1024
#define TY_ 4096
#define C_ 768
#define H_ 12
#define D_ 64
#define NSPLIT 8
#define KT 8

typedef __bf16 bf16x8 __attribute__((ext_vector_type(8)));
typedef float floatx4 __attribute__((ext_vector_type(4)));

__device__ __forceinline__ void async_copy16(const void* g, void* l) {
    __builtin_amdgcn_global_load_lds(
        (const __attribute__((address_space(1))) unsigned int*)g,
        (__attribute__((address_space(3))) unsigned int*)l,
        16, 0, 0);
}

// ---------------------------------------------------------------------------
// f32 -> bf16 elementwise convert (4 elems/thread)
// ---------------------------------------------------------------------------
__global__ __launch_bounds__(256)
void conv_bf16(const float* __restrict__ in, __bf16* __restrict__ out, int n)
{
    int i = (blockIdx.x * 256 + threadIdx.x) * 4;
    if (i < n) {
        float4 v = *(const float4*)(in + i);
        union { __bf16 h[4]; uint2 u; } p;
        p.h[0] = (__bf16)v.x; p.h[1] = (__bf16)v.y;
        p.h[2] = (__bf16)v.z; p.h[3] = (__bf16)v.w;
        *(uint2*)(out + i) = p.u;
    }
}

// ---------------------------------------------------------------------------
// W(K x N f32, row-major) -> Wt(N x K bf16, row-major), scaled.
// ---------------------------------------------------------------------------
__global__ __launch_bounds__(256)
void transp_bf16(const float* __restrict__ W, __bf16* __restrict__ Wt,
                 int K, int N, float scale)
{
    __shared__ float tile[32][33];
    const int bx = blockIdx.x * 32;   // n
    const int by = blockIdx.y * 32;   // k
    const int tx = threadIdx.x, ty = threadIdx.y;
#pragma unroll
    for (int i = 0; i < 4; i++)
        tile[ty + i * 8][tx] = W[(size_t)(by + ty + i * 8) * N + bx + tx];
    __syncthreads();
#pragma unroll
    for (int i = 0; i < 4; i++)
        Wt[(size_t)(bx + ty + i * 8) * K + by + tx] =
            (__bf16)(tile[tx][ty + i * 8] * scale);
}

// ---------------------------------------------------------------------------
// MFMA GEMM: C(M,N) = A(M,768 bf16) @ Bt(N,768 bf16)^T, f32 out w/ epilogue.
// 128x128 tile, BK=32, 4 waves (2x2 of 64x64), 16x16x32 MFMA.
// MODE 0: plain f32 store to out0
// MODE 1: rope(pos=t_arr[row]) -> out0          (Q path; 0.125 folded in Wq)
// MODE 2: col<C_: rope -> out0 (K); else -> out1 (V)
// ---------------------------------------------------------------------------
template<int MODE>
__global__ __launch_bounds__(256)
void mfma_gemm(const __bf16* __restrict__ A,
               const __bf16* __restrict__ Bt,
               float* __restrict__ out0,
               float* __restrict__ out1,
               const float* __restrict__ t_arr,
               const float* __restrict__ inv_freq,
               int N)
{
    const int K = C_;
    __shared__ __align__(16) __bf16 smem[8192];  // As[128*32] | Bs[128*32]
    __bf16* As = smem;
    __bf16* Bs = smem + 4096;

    const int tid  = threadIdx.x;
    const int wave = tid >> 6;
    const int lane = tid & 63;
    const int m16  = lane & 15;
    const int quad = lane >> 4;
    const int wm   = wave >> 1;        // 0..1
    const int wn   = wave & 1;         // 0..1
    const int row0 = blockIdx.y * 128;
    const int n0   = blockIdx.x * 128;

    floatx4 acc[4][4];
#pragma unroll
    for (int i = 0; i < 4; i++)
#pragma unroll
        for (int j = 0; j < 4; j++) acc[i][j] = (floatx4){0.f, 0.f, 0.f, 0.f};

    // staging addresses: round j covers LDS bytes [j*4096 + wave*1024 + lane*16)
    // element offset e = j*2048 + wave*512 + lane*8 ; row = e>>5, col = e&31
    int srow[4], scol[4];
#pragma unroll
    for (int j = 0; j < 4; j++) {
        int e = j * 2048 + wave * 512 + lane * 8;
        int e2 = e & 4095;
        srow[j] = e2 >> 5;
        scol[j] = e2 & 31;
    }

    for (int k0 = 0; k0 < K; k0 += 32) {
        __syncthreads();
#pragma unroll
        for (int j = 0; j < 4; j++) {
            const __bf16* src = (j < 2)
                ? A  + (size_t)(row0 + srow[j]) * K + (k0 + scol[j])
                : Bt + (size_t)(n0   + srow[j]) * K + (k0 + scol[j]);
            async_copy16(src, (char*)smem + j * 4096 + wave * 1024);
        }
        __syncthreads();

        bf16x8 af[4], bf[4];
#pragma unroll
        for (int i = 0; i < 4; i++)
            af[i] = *(const bf16x8*)(As + (size_t)(wm * 64 + i * 16 + m16) * 32 + quad * 8);
#pragma unroll
        for (int j = 0; j < 4; j++)
            bf[j] = *(const bf16x8*)(Bs + (size_t)(wn * 64 + j * 16 + m16) * 32 + quad * 8);
#pragma unroll
        for (int i = 0; i < 4; i++)
#pragma unroll
            for (int j = 0; j < 4; j++)
                acc[i][j] = __builtin_amdgcn_mfma_f32_16x16x32_bf16(af[i], bf[j], acc[i][j], 0, 0, 0);
    }

    // epilogue: elem (i,j,r): row = row0+wm*64+i*16+quad*4+r, col = n0+wn*64+j*16+m16
#pragma unroll
    for (int i = 0; i < 4; i++) {
#pragma unroll
        for (int j = 0; j < 4; j++) {
            const int col = n0 + wn * 64 + j * 16 + m16;
#pragma unroll
            for (int r = 0; r < 4; r++) {
                const int row = row0 + wm * 64 + i * 16 + quad * 4 + r;
                float v = acc[i][j][r];
                if (MODE == 0) {
                    out0[(size_t)row * C_ + col] = v;
                } else {
                    float vp = __shfl_xor(v, 1);
                    const bool isK = (MODE == 1) || (col < C_);
                    if (isK) {
                        const int cc = col & (D_ - 1);
                        const float fr = t_arr[row] * inv_freq[cc >> 1];
                        float sn, cs;
                        sincosf(fr, &sn, &cs);
                        const float res = (m16 & 1) ? (v * cs + vp * sn)
                                                    : (v * cs - vp * sn);
                        out0[(size_t)row * C_ + col] = res;
                    } else {
                        out1[(size_t)row * C_ + (col - C_)] = v;
                    }
                }
            }
        }
    }
}

// ---------------------------------------------------------------------------
// Attention: 1 thread per q row, wave=64 q rows/block; contiguous k-window
// via binary search; KT rows of K/V staged per barrier; NSPLIT k-splits.
// ---------------------------------------------------------------------------
__global__ __launch_bounds__(64)
void attn_kernel(const float* __restrict__ Q,
                 const float* __restrict__ Kr,
                 const float* __restrict__ V,
                 const float* __restrict__ x_t,
                 const float* __restrict__ y_t,
                 const int* __restrict__ dist_p,
                 const int* __restrict__ min_dist_p,
                 float* __restrict__ pacc,
                 float* __restrict__ pml)
{
    const int lane  = threadIdx.x;
    const int qt    = blockIdx.x;
    const int bh    = blockIdx.y;
    const int split = blockIdx.z;
    const int b = bh / H_, h = bh % H_;
    const int txg = qt * 64 + lane;

    const float dist = (float)dist_p[0];
    const float xt   = x_t[b * TX_ + txg] - (float)min_dist_p[0];
    const float* yt  = y_t + (size_t)b * TY_;

    int lo = 0, hi = TY_;
    while (lo < hi) { int mid = (lo + hi) >> 1; if (yt[mid] + dist < xt) lo = mid + 1; else hi = mid; }
    const int klo = lo;
    lo = 0; hi = TY_;
    while (lo < hi) { int mid = (lo + hi) >> 1; if (yt[mid] <= xt) lo = mid + 1; else hi = mid; }
    const int khi = lo - 1;

    int kmin = klo, kmax = khi;
#pragma unroll
    for (int off = 32; off; off >>= 1) {
        kmin = min(kmin, __shfl_xor(kmin, off, 64));
        kmax = max(kmax, __shfl_xor(kmax, off, 64));
    }
    const int len   = kmax - kmin + 1;
    const int chunk = (len + NSPLIT - 1) / NSPLIT;
    const int k0    = kmin + split * chunk;
    const int k1    = min(k0 + chunk, kmax + 1);

    float q[64];
    const float* qp = Q + (size_t)(b * TX_ + txg) * C_ + h * D_;
#pragma unroll
    for (int d = 0; d < 64; d += 4) {
        float4 t = *(const float4*)(qp + d);
        q[d] = t.x; q[d + 1] = t.y; q[d + 2] = t.z; q[d + 3] = t.w;
    }

    float m = -INFINITY, lsum = 0.f;
    float acc[64];
#pragma unroll
    for (int d = 0; d < 64; d++) acc[d] = 0.f;

    __shared__ float Ks[KT][64];
    __shared__ float Vs[KT][64];

    const int srow = lane >> 3;          // 0..7
    const int scol = (lane & 7) * 8;     // 0..56

    for (int kb = k0; kb < k1; kb += KT) {
        int kr = kb + srow;
        if (kr > TY_ - 1) kr = TY_ - 1;
        const size_t base = (size_t)(b * TY_ + kr) * C_ + h * D_ + scol;
        float4 k4a = *(const float4*)(Kr + base);
        float4 k4b = *(const float4*)(Kr + base + 4);
        float4 v4a = *(const float4*)(V + base);
        float4 v4b = *(const float4*)(V + base + 4);
        __syncthreads();
        *(float4*)&Ks[srow][scol]     = k4a;
        *(float4*)&Ks[srow][scol + 4] = k4b;
        *(float4*)&Vs[srow][scol]     = v4a;
        *(float4*)&Vs[srow][scol + 4] = v4b;
        __syncthreads();

        const int kend = min(k1, kb + KT);
        for (int k = kb; k < kend; ++k) {
            if (k < klo || k > khi) continue;
            const int kk = k - kb;
            float s0 = 0.f, s1 = 0.f, s2 = 0.f, s3 = 0.f;
#pragma unroll
            for (int d = 0; d < 64; d += 4) {
                s0 += q[d]     * Ks[kk][d];
                s1 += q[d + 1] * Ks[kk][d + 1];
                s2 += q[d + 2] * Ks[kk][d + 2];
                s3 += q[d + 3] * Ks[kk][d + 3];
            }
            const float s  = (s0 + s1) + (s2 + s3);
            const float mn = fmaxf(m, s);
            const float corr = __expf(m - mn);
            const float p    = __expf(s - mn);
            lsum = lsum * corr + p;
#pragma unroll
            for (int d = 0; d < 64; d++)
                acc[d] = acc[d] * corr + p * Vs[kk][d];
            m = mn;
        }
    }

    const size_t R = (size_t)B_ * H_ * TX_;
    const size_t r = (size_t)bh * TX_ + txg;
    float* pa = pacc + ((size_t)split * R + r) * 64;
#pragma unroll
    for (int d = 0; d < 64; d++) pa[d] = acc[d];
    pml[((size_t)split * R + r) * 2 + 0] = m;
    pml[((size_t)split * R + r) * 2 + 1] = lsum;
}

// ---------------------------------------------------------------------------
// Combine NSPLIT partials -> Ob (B,TX,C) as bf16 (input to proj GEMM)
// ---------------------------------------------------------------------------
__global__ __launch_bounds__(256)
void combine_kernel(const float* __restrict__ pacc,
                    const float* __restrict__ pml,
                    __bf16* __restrict__ O)
{
    const int d   = threadIdx.x;
    const int sub = threadIdx.y;
    const size_t R = (size_t)B_ * H_ * TX_;
    const size_t r = (size_t)blockIdx.x * 4 + sub;
    const int bh  = (int)(r / TX_);
    const int txg = (int)(r % TX_);
    const int b = bh / H_, h = bh % H_;

    float mv[NSPLIT], lv[NSPLIT];
    float M = -INFINITY;
#pragma unroll
    for (int s = 0; s < NSPLIT; s++) {
        mv[s] = pml[((size_t)s * R + r) * 2 + 0];
        lv[s] = pml[((size_t)s * R + r) * 2 + 1];
        if (lv[s] > 0.f) M = fmaxf(M, mv[s]);
    }
    float L = 0.f, val = 0.f;
#pragma unroll
    for (int s = 0; s < NSPLIT; s++) {
        if (lv[s] > 0.f) {
            const float w = __expf(mv[s] - M);
            L += lv[s] * w;
            val += pacc[((size_t)s * R + r) * 64 + d] * w;
        }
    }
    const float o = (L > 0.f) ? val / L : 0.f;
    O[(size_t)(b * TX_ + txg) * C_ + h * D_ + d] = (__bf16)o;
}

// ---------------------------------------------------------------------------
extern "C" void kernel_launch(void* const* d_in, const int* in_sizes, int n_in,
                              void* d_out, int out_size, void* d_ws, size_t ws_size,
                              hipStream_t stream)
{
    const float* x        = (const float*)d_in[0];
    const float* x_t      = (const float*)d_in[1];
    const float* y        = (const float*)d_in[2];
    const float* y_t      = (const float*)d_in[3];
    const int*   dist     = (const int*)d_in[4];
    const int*   min_dist = (const int*)d_in[5];
    const float* Wq       = (const float*)d_in[6];
    const float* Wkv      = (const float*)d_in[7];
    const float* Wproj    = (const float*)d_in[8];
    const float* inv_freq = (const float*)d_in[9];
    float* out = (float*)d_out;

    const size_t QN = (size_t)B_ * TX_ * C_;   // 1.57M
    const size_t KN = (size_t)B_ * TY_ * C_;   // 6.29M
    const size_t R  = (size_t)B_ * H_ * TX_;   // 24576

    float* ws = (float*)d_ws;
    float* Qb   = ws; ws += QN;
    float* Kb   = ws; ws += KN;
    float* Vb   = ws; ws += KN;
    float* pacc = ws; ws += (size_t)NSPLIT * R * 64;
    float* pml  = ws; ws += (size_t)NSPLIT * R * 2;
    __bf16* bws = (__bf16*)ws;
    __bf16* xb    = bws; bws += QN;
    __bf16* yb    = bws; bws += KN;
    __bf16* Wqt   = bws; bws += (size_t)C_ * C_;
    __bf16* Wkvt  = bws; bws += (size_t)C_ * 2 * C_;
    __bf16* Wprt  = bws; bws += (size_t)C_ * C_;
    __bf16* Ob    = bws; bws += QN;

    // --- prep: bf16 conversions + weight transposes ---
    conv_bf16<<<dim3((unsigned)(QN / 1024)), dim3(256), 0, stream>>>(x, xb, (int)QN);
    conv_bf16<<<dim3((unsigned)(KN / 1024)), dim3(256), 0, stream>>>(y, yb, (int)KN);
    transp_bf16<<<dim3(C_ / 32, C_ / 32), dim3(32, 8), 0, stream>>>(Wq, Wqt, C_, C_, 0.125f);
    transp_bf16<<<dim3(2 * C_ / 32, C_ / 32), dim3(32, 8), 0, stream>>>(Wkv, Wkvt, C_, 2 * C_, 1.0f);
    transp_bf16<<<dim3(C_ / 32, C_ / 32), dim3(32, 8), 0, stream>>>(Wproj, Wprt, C_, C_, 1.0f);

    // --- Q = rope(x @ Wq) * 0.125 (scale folded into Wqt) ---
    mfma_gemm<1><<<dim3(C_ / 128, (B_ * TX_) / 128), dim3(256), 0, stream>>>(
        xb, Wqt, Qb, nullptr, x_t, inv_freq, C_);
    // --- K = rope(y @ Wkv[:, :C]), V = y @ Wkv[:, C:] ---
    mfma_gemm<2><<<dim3(2 * C_ / 128, (B_ * TY_) / 128), dim3(256), 0, stream>>>(
        yb, Wkvt, Kb, Vb, y_t, inv_freq, 2 * C_);
    // --- masked flash attention, k-split ---
    attn_kernel<<<dim3(TX_ / 64, B_ * H_, NSPLIT), dim3(64), 0, stream>>>(
        Qb, Kb, Vb, x_t, y_t, dist, min_dist, pacc, pml);
    // --- combine partials -> Ob (bf16) ---
    combine_kernel<<<dim3((unsigned)(R / 4)), dim3(64, 4), 0, stream>>>(
        pacc, pml, Ob);
    // --- out = O @ Wproj ---
    mfma_gemm<0><<<dim3(C_ / 128, (B_ * TX_) / 128), dim3(256), 0, stream>>>(
        Ob, Wprt, out, nullptr, nullptr, nullptr, C_);
}

// Round 3
// 345.484 us; speedup vs baseline: 1.9968x; 1.6385x over previous
//
#include <hip/hip_runtime.h>
#include <hip/hip_bf16.h>
#include <math.h>

#define B_ 2
#define TX_ 1024
#define TY_ 4096
#define C_ 768
#define H_ 12
#define D_ 64
#define NSPLIT 8
#define KT 8

typedef __bf16 bf16x8 __attribute__((ext_vector_type(8)));
typedef float floatx4 __attribute__((ext_vector_type(4)));

__device__ __forceinline__ void async_copy16(const void* g, void* l) {
    __builtin_amdgcn_global_load_lds(
        (const __attribute__((address_space(1))) unsigned int*)g,
        (__attribute__((address_space(3))) unsigned int*)l,
        16, 0, 0);
}

// ---------------------------------------------------------------------------
// f32 -> bf16 elementwise convert (4 elems/thread)
// ---------------------------------------------------------------------------
__global__ __launch_bounds__(256)
void conv_bf16(const float* __restrict__ in, __bf16* __restrict__ out, int n)
{
    int i = (blockIdx.x * 256 + threadIdx.x) * 4;
    if (i < n) {
        float4 v = *(const float4*)(in + i);
        union { __bf16 h[4]; uint2 u; } p;
        p.h[0] = (__bf16)v.x; p.h[1] = (__bf16)v.y;
        p.h[2] = (__bf16)v.z; p.h[3] = (__bf16)v.w;
        *(uint2*)(out + i) = p.u;
    }
}

// ---------------------------------------------------------------------------
// W(K x N f32, row-major) -> Wt(N x K bf16, row-major), scaled.
// ---------------------------------------------------------------------------
__global__ __launch_bounds__(256)
void transp_bf16(const float* __restrict__ W, __bf16* __restrict__ Wt,
                 int K, int N, float scale)
{
    __shared__ float tile[32][33];
    const int bx = blockIdx.x * 32;   // n
    const int by = blockIdx.y * 32;   // k
    const int tx = threadIdx.x, ty = threadIdx.y;
#pragma unroll
    for (int i = 0; i < 4; i++)
        tile[ty + i * 8][tx] = W[(size_t)(by + ty + i * 8) * N + bx + tx];
    __syncthreads();
#pragma unroll
    for (int i = 0; i < 4; i++)
        Wt[(size_t)(bx + ty + i * 8) * K + by + tx] =
            (__bf16)(tile[tx][ty + i * 8] * scale);
}

// ---------------------------------------------------------------------------
// MFMA GEMM: C(M,N) = A(M,768 bf16) @ Bt(N,768 bf16)^T, f32 out.
// 128x128 tile, BK=32, 4 waves (2x2 of 64x64), 16x16x32 MFMA.
// Epilogue staged through LDS -> full-128B-line coalesced float4 stores.
// MODE 0: plain store. MODE 1: rope all cols (Q). MODE 2: block-uniform
// K (rope, n0<C_) / V (plain, n0>=C_) split.
// ---------------------------------------------------------------------------
template<int MODE>
__global__ __launch_bounds__(256)
void mfma_gemm(const __bf16* __restrict__ A,
               const __bf16* __restrict__ Bt,
               float* __restrict__ out0,
               float* __restrict__ out1,
               const float* __restrict__ t_arr,
               const float* __restrict__ inv_freq,
               int N)
{
    const int K = C_;
    __shared__ __align__(16) float smem_f[4224];   // 16896 B
    __bf16* As = (__bf16*)smem_f;                   // [128*32]
    __bf16* Bs = As + 4096;                         // [128*32]

    const int tid  = threadIdx.x;
    const int wave = tid >> 6;
    const int lane = tid & 63;
    const int m16  = lane & 15;
    const int quad = lane >> 4;
    const int wm   = wave >> 1;
    const int wn   = wave & 1;
    const int row0 = blockIdx.y * 128;
    const int n0   = blockIdx.x * 128;

    floatx4 acc[4][4];
#pragma unroll
    for (int i = 0; i < 4; i++)
#pragma unroll
        for (int j = 0; j < 4; j++) acc[i][j] = (floatx4){0.f, 0.f, 0.f, 0.f};

    int srow[4], scol[4];
#pragma unroll
    for (int j = 0; j < 4; j++) {
        int e = j * 2048 + wave * 512 + lane * 8;
        int e2 = e & 4095;
        srow[j] = e2 >> 5;
        scol[j] = e2 & 31;
    }

    for (int k0 = 0; k0 < K; k0 += 32) {
        __syncthreads();
#pragma unroll
        for (int j = 0; j < 4; j++) {
            const __bf16* src = (j < 2)
                ? A  + (size_t)(row0 + srow[j]) * K + (k0 + scol[j])
                : Bt + (size_t)(n0   + srow[j]) * K + (k0 + scol[j]);
            async_copy16(src, (char*)smem_f + j * 4096 + wave * 1024);
        }
        __syncthreads();

        bf16x8 af[4], bfr[4];
#pragma unroll
        for (int i = 0; i < 4; i++)
            af[i] = *(const bf16x8*)(As + (size_t)(wm * 64 + i * 16 + m16) * 32 + quad * 8);
#pragma unroll
        for (int j = 0; j < 4; j++)
            bfr[j] = *(const bf16x8*)(Bs + (size_t)(wn * 64 + j * 16 + m16) * 32 + quad * 8);
#pragma unroll
        for (int i = 0; i < 4; i++)
#pragma unroll
            for (int j = 0; j < 4; j++)
                acc[i][j] = __builtin_amdgcn_mfma_f32_16x16x32_bf16(af[i], bfr[j], acc[i][j], 0, 0, 0);
    }

    // ---- epilogue: LDS-staged, full-line coalesced stores ----
    const int STR = 132;                     // 32x132 f32 = 16896 B
    float* fs = smem_f;

    float* outp; int ncol0; bool doRope;
    if (MODE == 0)      { outp = out0; ncol0 = n0; doRope = false; }
    else if (MODE == 1) { outp = out0; ncol0 = n0; doRope = true; }
    else {
        if (n0 < C_) { outp = out0; ncol0 = n0;      doRope = true;  }
        else         { outp = out1; ncol0 = n0 - C_; doRope = false; }
    }

#pragma unroll
    for (int i = 0; i < 4; i++) {
        __syncthreads();                     // fs reuse safety
#pragma unroll
        for (int j = 0; j < 4; j++) {
            const int col_l = wn * 64 + j * 16 + m16;
#pragma unroll
            for (int r = 0; r < 4; r++) {
                const int row_l = quad * 4 + r;
                float v = acc[i][j][r];
                if (doRope) {
                    const float vp = __shfl_xor(v, 1);
                    const int row = row0 + wm * 64 + i * 16 + row_l;
                    const int cc = (ncol0 + col_l) & (D_ - 1);
                    const float fr = t_arr[row] * inv_freq[cc >> 1];
                    const float sn = __sinf(fr), cs = __cosf(fr);
                    v = (m16 & 1) ? (v * cs + vp * sn) : (v * cs - vp * sn);
                }
                fs[(wm * 16 + row_l) * STR + col_l] = v;
            }
        }
        __syncthreads();
        {
            const int r32 = tid >> 3;                 // 0..31
            const int lc  = (tid & 7) * 4;            // 0..28
            const int row = row0 + (r32 >> 4) * 64 + i * 16 + (r32 & 15);
            float* gp = outp + (size_t)row * C_ + ncol0;
#pragma unroll
            for (int c2 = 0; c2 < 4; c2++) {
                float4 v4 = *(const float4*)&fs[r32 * STR + c2 * 32 + lc];
                *(float4*)(gp + c2 * 32 + lc) = v4;
            }
        }
    }
}

// ---------------------------------------------------------------------------
// Attention: 1 thread per q row, wave=64 q rows/block; contiguous k-window
// via binary search; KT rows of K/V staged per barrier; NSPLIT k-splits.
// ---------------------------------------------------------------------------
__global__ __launch_bounds__(64)
void attn_kernel(const float* __restrict__ Q,
                 const float* __restrict__ Kr,
                 const float* __restrict__ V,
                 const float* __restrict__ x_t,
                 const float* __restrict__ y_t,
                 const int* __restrict__ dist_p,
                 const int* __restrict__ min_dist_p,
                 float* __restrict__ pacc,
                 float* __restrict__ pml)
{
    const int lane  = threadIdx.x;
    const int qt    = blockIdx.x;
    const int bh    = blockIdx.y;
    const int split = blockIdx.z;
    const int b = bh / H_, h = bh % H_;
    const int txg = qt * 64 + lane;

    const float dist = (float)dist_p[0];
    const float xt   = x_t[b * TX_ + txg] - (float)min_dist_p[0];
    const float* yt  = y_t + (size_t)b * TY_;

    int lo = 0, hi = TY_;
    while (lo < hi) { int mid = (lo + hi) >> 1; if (yt[mid] + dist < xt) lo = mid + 1; else hi = mid; }
    const int klo = lo;
    lo = 0; hi = TY_;
    while (lo < hi) { int mid = (lo + hi) >> 1; if (yt[mid] <= xt) lo = mid + 1; else hi = mid; }
    const int khi = lo - 1;

    int kmin = klo, kmax = khi;
#pragma unroll
    for (int off = 32; off; off >>= 1) {
        kmin = min(kmin, __shfl_xor(kmin, off, 64));
        kmax = max(kmax, __shfl_xor(kmax, off, 64));
    }
    const int len   = kmax - kmin + 1;
    const int chunk = (len + NSPLIT - 1) / NSPLIT;
    const int k0    = kmin + split * chunk;
    const int k1    = min(k0 + chunk, kmax + 1);

    float q[64];
    const float* qp = Q + (size_t)(b * TX_ + txg) * C_ + h * D_;
#pragma unroll
    for (int d = 0; d < 64; d += 4) {
        float4 t = *(const float4*)(qp + d);
        q[d] = t.x; q[d + 1] = t.y; q[d + 2] = t.z; q[d + 3] = t.w;
    }

    float m = -INFINITY, lsum = 0.f;
    float acc[64];
#pragma unroll
    for (int d = 0; d < 64; d++) acc[d] = 0.f;

    __shared__ float Ks[KT][64];
    __shared__ float Vs[KT][64];

    const int srow = lane >> 3;
    const int scol = (lane & 7) * 8;

    for (int kb = k0; kb < k1; kb += KT) {
        int kr = kb + srow;
        if (kr > TY_ - 1) kr = TY_ - 1;
        const size_t base = (size_t)(b * TY_ + kr) * C_ + h * D_ + scol;
        float4 k4a = *(const float4*)(Kr + base);
        float4 k4b = *(const float4*)(Kr + base + 4);
        float4 v4a = *(const float4*)(V + base);
        float4 v4b = *(const float4*)(V + base + 4);
        __syncthreads();
        *(float4*)&Ks[srow][scol]     = k4a;
        *(float4*)&Ks[srow][scol + 4] = k4b;
        *(float4*)&Vs[srow][scol]     = v4a;
        *(float4*)&Vs[srow][scol + 4] = v4b;
        __syncthreads();

        const int kend = min(k1, kb + KT);
        for (int k = kb; k < kend; ++k) {
            if (k < klo || k > khi) continue;
            const int kk = k - kb;
            float s0 = 0.f, s1 = 0.f, s2 = 0.f, s3 = 0.f;
#pragma unroll
            for (int d = 0; d < 64; d += 4) {
                s0 += q[d]     * Ks[kk][d];
                s1 += q[d + 1] * Ks[kk][d + 1];
                s2 += q[d + 2] * Ks[kk][d + 2];
                s3 += q[d + 3] * Ks[kk][d + 3];
            }
            const float s  = (s0 + s1) + (s2 + s3);
            const float mn = fmaxf(m, s);
            const float corr = __expf(m - mn);
            const float p    = __expf(s - mn);
            lsum = lsum * corr + p;
#pragma unroll
            for (int d = 0; d < 64; d++)
                acc[d] = acc[d] * corr + p * Vs[kk][d];
            m = mn;
        }
    }

    const size_t R = (size_t)B_ * H_ * TX_;
    const size_t r = (size_t)bh * TX_ + txg;
    float* pa = pacc + ((size_t)split * R + r) * 64;
#pragma unroll
    for (int d = 0; d < 64; d++) pa[d] = acc[d];
    pml[((size_t)split * R + r) * 2 + 0] = m;
    pml[((size_t)split * R + r) * 2 + 1] = lsum;
}

// ---------------------------------------------------------------------------
// Combine NSPLIT partials -> Ob (B,TX,C) as bf16 (input to proj GEMM)
// ---------------------------------------------------------------------------
__global__ __launch_bounds__(256)
void combine_kernel(const float* __restrict__ pacc,
                    const float* __restrict__ pml,
                    __bf16* __restrict__ O)
{
    const int d   = threadIdx.x;
    const int sub = threadIdx.y;
    const size_t R = (size_t)B_ * H_ * TX_;
    const size_t r = (size_t)blockIdx.x * 4 + sub;
    const int bh  = (int)(r / TX_);
    const int txg = (int)(r % TX_);
    const int b = bh / H_, h = bh % H_;

    float mv[NSPLIT], lv[NSPLIT];
    float M = -INFINITY;
#pragma unroll
    for (int s = 0; s < NSPLIT; s++) {
        mv[s] = pml[((size_t)s * R + r) * 2 + 0];
        lv[s] = pml[((size_t)s * R + r) * 2 + 1];
        if (lv[s] > 0.f) M = fmaxf(M, mv[s]);
    }
    float L = 0.f, val = 0.f;
#pragma unroll
    for (int s = 0; s < NSPLIT; s++) {
        if (lv[s] > 0.f) {
            const float w = __expf(mv[s] - M);
            L += lv[s] * w;
            val += pacc[((size_t)s * R + r) * 64 + d] * w;
        }
    }
    const float o = (L > 0.f) ? val / L : 0.f;
    O[(size_t)(b * TX_ + txg) * C_ + h * D_ + d] = (__bf16)o;
}

// ---------------------------------------------------------------------------
extern "C" void kernel_launch(void* const* d_in, const int* in_sizes, int n_in,
                              void* d_out, int out_size, void* d_ws, size_t ws_size,
                              hipStream_t stream)
{
    const float* x        = (const float*)d_in[0];
    const float* x_t      = (const float*)d_in[1];
    const float* y        = (const float*)d_in[2];
    const float* y_t      = (const float*)d_in[3];
    const int*   dist     = (const int*)d_in[4];
    const int*   min_dist = (const int*)d_in[5];
    const float* Wq       = (const float*)d_in[6];
    const float* Wkv      = (const float*)d_in[7];
    const float* Wproj    = (const float*)d_in[8];
    const float* inv_freq = (const float*)d_in[9];
    float* out = (float*)d_out;

    const size_t QN = (size_t)B_ * TX_ * C_;
    const size_t KN = (size_t)B_ * TY_ * C_;
    const size_t R  = (size_t)B_ * H_ * TX_;

    float* ws = (float*)d_ws;
    float* Qb   = ws; ws += QN;
    float* Kb   = ws; ws += KN;
    float* Vb   = ws; ws += KN;
    float* pacc = ws; ws += (size_t)NSPLIT * R * 64;
    float* pml  = ws; ws += (size_t)NSPLIT * R * 2;
    __bf16* bws = (__bf16*)ws;
    __bf16* xb    = bws; bws += QN;
    __bf16* yb    = bws; bws += KN;
    __bf16* Wqt   = bws; bws += (size_t)C_ * C_;
    __bf16* Wkvt  = bws; bws += (size_t)C_ * 2 * C_;
    __bf16* Wprt  = bws; bws += (size_t)C_ * C_;
    __bf16* Ob    = bws; bws += QN;

    conv_bf16<<<dim3((unsigned)(QN / 1024)), dim3(256), 0, stream>>>(x, xb, (int)QN);
    conv_bf16<<<dim3((unsigned)(KN / 1024)), dim3(256), 0, stream>>>(y, yb, (int)KN);
    transp_bf16<<<dim3(C_ / 32, C_ / 32), dim3(32, 8), 0, stream>>>(Wq, Wqt, C_, C_, 0.125f);
    transp_bf16<<<dim3(2 * C_ / 32, C_ / 32), dim3(32, 8), 0, stream>>>(Wkv, Wkvt, C_, 2 * C_, 1.0f);
    transp_bf16<<<dim3(C_ / 32, C_ / 32), dim3(32, 8), 0, stream>>>(Wproj, Wprt, C_, C_, 1.0f);

    mfma_gemm<1><<<dim3(C_ / 128, (B_ * TX_) / 128), dim3(256), 0, stream>>>(
        xb, Wqt, Qb, nullptr, x_t, inv_freq, C_);
    mfma_gemm<2><<<dim3(2 * C_ / 128, (B_ * TY_) / 128), dim3(256), 0, stream>>>(
        yb, Wkvt, Kb, Vb, y_t, inv_freq, 2 * C_);
    attn_kernel<<<dim3(TX_ / 64, B_ * H_, NSPLIT), dim3(64), 0, stream>>>(
        Qb, Kb, Vb, x_t, y_t, dist, min_dist, pacc, pml);
    combine_kernel<<<dim3((unsigned)(R / 4)), dim3(64, 4), 0, stream>>>(
        pacc, pml, Ob);
    mfma_gemm<0><<<dim3(C_ / 128, (B_ * TX_) / 128), dim3(256), 0, stream>>>(
        Ob, Wprt, out, nullptr, nullptr, nullptr, C_);
}

// Round 5
// 245.286 us; speedup vs baseline: 2.8124x; 1.4085x over previous
//
#include <hip/hip_runtime.h>
#include <hip/hip_bf16.h>
#include <math.h>

#define B_ 2
#define TX_ 1024
#define TY_ 4096
#define C_ 768
#define H_ 12
#define D_ 64
#define NSPLIT 4

typedef __bf16 bf16x8 __attribute__((ext_vector_type(8)));
typedef float floatx4 __attribute__((ext_vector_type(4)));

__device__ __forceinline__ void async_copy16(const void* g, void* l) {
    __builtin_amdgcn_global_load_lds(
        (const __attribute__((address_space(1))) unsigned int*)g,
        (__attribute__((address_space(3))) unsigned int*)l,
        16, 0, 0);
}

__device__ __forceinline__ bf16x8 cvt8(const float* s) {
    bf16x8 r;
#pragma unroll
    for (int i = 0; i < 8; i++) r[i] = (__bf16)s[i];
    return r;
}

// ---------------------------------------------------------------------------
// f32 -> bf16 elementwise convert
// ---------------------------------------------------------------------------
__global__ __launch_bounds__(256)
void conv_bf16(const float* __restrict__ in, __bf16* __restrict__ out, int n)
{
    int i = (blockIdx.x * 256 + threadIdx.x) * 4;
    if (i < n) {
        float4 v = *(const float4*)(in + i);
        union { __bf16 h[4]; uint2 u; } p;
        p.h[0] = (__bf16)v.x; p.h[1] = (__bf16)v.y;
        p.h[2] = (__bf16)v.z; p.h[3] = (__bf16)v.w;
        *(uint2*)(out + i) = p.u;
    }
}

// ---------------------------------------------------------------------------
// W(K x N f32) -> Wt(N x K bf16), scaled.
// ---------------------------------------------------------------------------
__global__ __launch_bounds__(256)
void transp_bf16(const float* __restrict__ W, __bf16* __restrict__ Wt,
                 int K, int N, float scale)
{
    __shared__ float tile[32][33];
    const int bx = blockIdx.x * 32;
    const int by = blockIdx.y * 32;
    const int tx = threadIdx.x, ty = threadIdx.y;
#pragma unroll
    for (int i = 0; i < 4; i++)
        tile[ty + i * 8][tx] = W[(size_t)(by + ty + i * 8) * N + bx + tx];
    __syncthreads();
#pragma unroll
    for (int i = 0; i < 4; i++)
        Wt[(size_t)(bx + ty + i * 8) * K + by + tx] =
            (__bf16)(tile[tx][ty + i * 8] * scale);
}

// ---------------------------------------------------------------------------
// MFMA GEMM, 128x128 tile, BK=32, 2x2 waves. LDS-staged epilogue.
// MODE 0: f32 plain -> out0 (proj)
// MODE 1: rope -> bf16 head-major [bh][TX][64] (Q)
// MODE 2: n0<C_: rope -> bf16 head-major [bh][TY][64] (K)
//         n0>=C_: bf16 transposed [bh][64][TY] (V)
// ---------------------------------------------------------------------------
template<int MODE>
__global__ __launch_bounds__(256)
void mfma_gemm(const __bf16* __restrict__ A,
               const __bf16* __restrict__ Bt,
               float* __restrict__ out0,
               __bf16* __restrict__ outb0,
               __bf16* __restrict__ outb1,
               const float* __restrict__ t_arr,
               const float* __restrict__ inv_freq,
               int N)
{
    const int K = C_;
    __shared__ __align__(16) float smem_f[4224];   // 16896 B
    __bf16* As = (__bf16*)smem_f;
    __bf16* Bs = As + 4096;

    const int tid  = threadIdx.x;
    const int wave = tid >> 6;
    const int lane = tid & 63;
    const int m16  = lane & 15;
    const int quad = lane >> 4;
    const int wm   = wave >> 1;
    const int wn   = wave & 1;
    const int row0 = blockIdx.y * 128;
    const int n0   = blockIdx.x * 128;

    floatx4 acc[4][4];
#pragma unroll
    for (int i = 0; i < 4; i++)
#pragma unroll
        for (int j = 0; j < 4; j++) acc[i][j] = (floatx4){0.f, 0.f, 0.f, 0.f};

    int srow[4], scol[4];
#pragma unroll
    for (int j = 0; j < 4; j++) {
        int e = j * 2048 + wave * 512 + lane * 8;
        int e2 = e & 4095;
        srow[j] = e2 >> 5;
        scol[j] = e2 & 31;
    }

    for (int k0 = 0; k0 < K; k0 += 32) {
        __syncthreads();
#pragma unroll
        for (int j = 0; j < 4; j++) {
            const __bf16* src = (j < 2)
                ? A  + (size_t)(row0 + srow[j]) * K + (k0 + scol[j])
                : Bt + (size_t)(n0   + srow[j]) * K + (k0 + scol[j]);
            async_copy16(src, (char*)smem_f + j * 4096 + wave * 1024);
        }
        __syncthreads();

        bf16x8 af[4], bfr[4];
#pragma unroll
        for (int i = 0; i < 4; i++)
            af[i] = *(const bf16x8*)(As + (size_t)(wm * 64 + i * 16 + m16) * 32 + quad * 8);
#pragma unroll
        for (int j = 0; j < 4; j++)
            bfr[j] = *(const bf16x8*)(Bs + (size_t)(wn * 64 + j * 16 + m16) * 32 + quad * 8);
#pragma unroll
        for (int i = 0; i < 4; i++)
#pragma unroll
            for (int j = 0; j < 4; j++)
                acc[i][j] = __builtin_amdgcn_mfma_f32_16x16x32_bf16(af[i], bfr[j], acc[i][j], 0, 0, 0);
    }

    // ---- epilogue ----
    const int STR = 132;
    float* fs = smem_f;
    const bool isK = (MODE == 1) || (MODE == 2 && n0 < C_);
    const bool doRope = (MODE != 0) && isK;

#pragma unroll
    for (int i = 0; i < 4; i++) {
        __syncthreads();
#pragma unroll
        for (int j = 0; j < 4; j++) {
            const int col_l = wn * 64 + j * 16 + m16;
#pragma unroll
            for (int r = 0; r < 4; r++) {
                const int row_l = quad * 4 + r;
                float v = acc[i][j][r];
                if (doRope) {
                    const float vp = __shfl_xor(v, 1);
                    const int row = row0 + wm * 64 + i * 16 + row_l;
                    const int cc = (n0 + col_l) & (D_ - 1);
                    const float fr = t_arr[row] * inv_freq[cc >> 1];
                    const float sn = __sinf(fr), cs = __cosf(fr);
                    v = (m16 & 1) ? (v * cs + vp * sn) : (v * cs - vp * sn);
                }
                fs[(wm * 16 + row_l) * STR + col_l] = v;
            }
        }
        __syncthreads();

        if (MODE == 0) {
            const int r32 = tid >> 3;
            const int lc  = (tid & 7) * 4;
            const int row = row0 + (r32 >> 4) * 64 + i * 16 + (r32 & 15);
            float* gp = out0 + (size_t)row * C_ + n0;
#pragma unroll
            for (int c2 = 0; c2 < 4; c2++) {
                float4 v4 = *(const float4*)&fs[r32 * STR + c2 * 32 + lc];
                *(float4*)(gp + c2 * 32 + lc) = v4;
            }
        } else if (isK) {
            // bf16 head-major [bh][T][64]
            const int T   = (MODE == 1) ? TX_ : TY_;
            const int TSH = (MODE == 1) ? 10 : 12;
            const int r32 = tid >> 3;
            const int lane8 = tid & 7;
            const int grow = row0 + (r32 >> 4) * 64 + i * 16 + (r32 & 15);
            const int bb = grow >> TSH;
            const int rk = grow & (T - 1);
            const int h  = (n0 >> 6) + (lane8 >> 2);
            const int d0 = (lane8 & 3) * 16;
            __bf16* gp = outb0 + ((size_t)(bb * H_ + h) * T + rk) * 64 + d0;
            const float* sp = &fs[r32 * STR + lane8 * 16];
            *(bf16x8*)gp       = cvt8(sp);
            *(bf16x8*)(gp + 8) = cvt8(sp + 8);
        } else {
            // V transposed bf16 [bh][64][TY]
            const int dcol = tid >> 1;
            const int g16  = tid & 1;            // which 16-row group
            const int h  = ((n0 - C_) >> 6) + (dcol >> 6);
            const int dd = dcol & 63;
            const int kbase = row0 + g16 * 64 + i * 16;
            const int bb  = kbase >> 12;
            const int kin = kbase & (TY_ - 1);
            float tmp[16];
#pragma unroll
            for (int jj = 0; jj < 16; jj++)
                tmp[jj] = fs[(g16 * 16 + jj) * STR + dcol];
            __bf16* gp = outb1 + ((size_t)(bb * H_ + h) * 64 + dd) * TY_ + kin;
            *(bf16x8*)gp       = cvt8(tmp);
            *(bf16x8*)(gp + 8) = cvt8(tmp + 8);
        }
    }
}

// ---------------------------------------------------------------------------
// MFMA flash attention. Block = 4 waves = 64 q rows. Chunk = 32 k rows.
// Q,K bf16 [bh][row][64]; V bf16 transposed [bh][64][TY].
// Elementwise time-based masking (same float predicates as reference).
// ---------------------------------------------------------------------------
__global__ __launch_bounds__(256)
void attn_mfma(const __bf16* __restrict__ Qb,
               const __bf16* __restrict__ Kb,
               const __bf16* __restrict__ Vt,
               const float* __restrict__ x_t,
               const float* __restrict__ y_t,
               const int* __restrict__ dist_p,
               const int* __restrict__ min_dist_p,
               float* __restrict__ pacc,
               float* __restrict__ pml)
{
    __shared__ __align__(16) __bf16 Kc[32 * 64];   // [k][d]
    __shared__ __align__(16) __bf16 Vc[64 * 32];   // [d][k]
    __shared__ __align__(16) __bf16 Pt[4][16 * 32];

    const int tid  = threadIdx.x;
    const int wave = tid >> 6;
    const int lane = tid & 63;
    const int m16  = lane & 15;
    const int quad = lane >> 4;
    const int qt = blockIdx.x, bh = blockIdx.y, split = blockIdx.z;
    const int b = bh / H_;
    const int qblk  = qt * 64;
    const int qbase = qblk + wave * 16;

    const float dist = (float)dist_p[0];
    const float md   = (float)min_dist_p[0];
    const float* yt = y_t + (size_t)b * TY_;
    const float* xt = x_t + (size_t)b * TX_;

    // block k-window (union over 64 sorted q rows)
    const float xtmin = xt[qblk] - md;
    const float xtmax = xt[qblk + 63] - md;
    int lo = 0, hi = TY_;
    while (lo < hi) { int mid = (lo + hi) >> 1; if (yt[mid] + dist < xtmin) lo = mid + 1; else hi = mid; }
    const int klo = lo;
    lo = 0; hi = TY_;
    while (lo < hi) { int mid = (lo + hi) >> 1; if (yt[mid] <= xtmax) lo = mid + 1; else hi = mid; }
    const int khi = lo - 1;
    const int len = khi - klo + 1;

    int k0 = klo, k1 = klo;
    if (len > 0) {
        const int cnt = (len + NSPLIT - 1) / NSPLIT;
        k0 = klo + split * cnt;
        k1 = min(k0 + cnt, klo + len);
    }

    float xtq[4];
#pragma unroll
    for (int r = 0; r < 4; r++)
        xtq[r] = xt[qbase + quad * 4 + r] - md;

    const __bf16* qp = Qb + ((size_t)bh * TX_ + qbase + m16) * 64;
    const bf16x8 aq0 = *(const bf16x8*)(qp + quad * 8);
    const bf16x8 aq1 = *(const bf16x8*)(qp + 32 + quad * 8);

    float m[4], l[4];
    floatx4 o[4];
#pragma unroll
    for (int r = 0; r < 4; r++) { m[r] = -3e38f; l[r] = 0.f; }
#pragma unroll
    for (int t = 0; t < 4; t++) o[t] = (floatx4){0.f, 0.f, 0.f, 0.f};

    for (int kc = k0; kc < k1; kc += 32) {
        const float yt0 = yt[min(kc + m16, TY_ - 1)];
        const float yt1 = yt[min(kc + 16 + m16, TY_ - 1)];

        __syncthreads();
        {
            const int krow = tid >> 3;
            const int kg = min(kc + krow, TY_ - 1);
            async_copy16(Kb + ((size_t)bh * TY_ + kg) * 64 + (tid & 7) * 8,
                         (char*)Kc + tid * 16);
            const int d = tid >> 2;
            const int kv = min(kc + (tid & 3) * 8, TY_ - 8);
            async_copy16(Vt + ((size_t)bh * 64 + d) * TY_ + kv,
                         (char*)Vc + tid * 16);
        }
        __syncthreads();

        // QK^T: S[16q x 32k] as two 16-col halves
        const bf16x8 bk0h0 = *(const bf16x8*)(Kc + m16 * 64 + quad * 8);
        const bf16x8 bk1h0 = *(const bf16x8*)(Kc + m16 * 64 + 32 + quad * 8);
        const bf16x8 bk0h1 = *(const bf16x8*)(Kc + (16 + m16) * 64 + quad * 8);
        const bf16x8 bk1h1 = *(const bf16x8*)(Kc + (16 + m16) * 64 + 32 + quad * 8);
        floatx4 s0 = (floatx4){0.f, 0.f, 0.f, 0.f};
        floatx4 s1 = (floatx4){0.f, 0.f, 0.f, 0.f};
        s0 = __builtin_amdgcn_mfma_f32_16x16x32_bf16(aq0, bk0h0, s0, 0, 0, 0);
        s0 = __builtin_amdgcn_mfma_f32_16x16x32_bf16(aq1, bk1h0, s0, 0, 0, 0);
        s1 = __builtin_amdgcn_mfma_f32_16x16x32_bf16(aq0, bk0h1, s1, 0, 0, 0);
        s1 = __builtin_amdgcn_mfma_f32_16x16x32_bf16(aq1, bk1h1, s1, 0, 0, 0);

        const int kg0 = kc + m16;
        const int kg1 = kc + 16 + m16;
        float p0[4], p1[4];
#pragma unroll
        for (int r = 0; r < 4; r++) {
            const bool v0 = (kg0 < k1) && (xtq[r] >= yt0) && (xtq[r] <= yt0 + dist);
            const bool v1 = (kg1 < k1) && (xtq[r] >= yt1) && (xtq[r] <= yt1 + dist);
            const float sm0 = v0 ? s0[r] : -3e38f;
            const float sm1 = v1 ? s1[r] : -3e38f;
            float rmax = fmaxf(sm0, sm1);
#pragma unroll
            for (int w = 1; w < 16; w <<= 1)
                rmax = fmaxf(rmax, __shfl_xor(rmax, w));
            const float mn = fmaxf(m[r], rmax);
            const float corr = __expf(m[r] - mn);
            p0[r] = v0 ? (float)(__bf16)__expf(sm0 - mn) : 0.f;
            p1[r] = v1 ? (float)(__bf16)__expf(sm1 - mn) : 0.f;
            float ps = p0[r] + p1[r];
#pragma unroll
            for (int w = 1; w < 16; w <<= 1)
                ps += __shfl_xor(ps, w);
            l[r] = l[r] * corr + ps;
            m[r] = mn;
#pragma unroll
            for (int t = 0; t < 4; t++) o[t][r] *= corr;
        }

        // P -> LDS (C-layout) -> A-layout
        __bf16* pt = Pt[wave];
#pragma unroll
        for (int r = 0; r < 4; r++) {
            pt[(quad * 4 + r) * 32 + m16]      = (__bf16)p0[r];
            pt[(quad * 4 + r) * 32 + 16 + m16] = (__bf16)p1[r];
        }
        const bf16x8 ap = *(const bf16x8*)(pt + m16 * 32 + quad * 8);
#pragma unroll
        for (int t = 0; t < 4; t++) {
            const bf16x8 bv = *(const bf16x8*)(Vc + (t * 16 + m16) * 32 + quad * 8);
            o[t] = __builtin_amdgcn_mfma_f32_16x16x32_bf16(ap, bv, o[t], 0, 0, 0);
        }
    }

    const size_t R = (size_t)B_ * H_ * TX_;
#pragma unroll
    for (int t = 0; t < 4; t++)
#pragma unroll
        for (int r = 0; r < 4; r++) {
            const size_t gr = (size_t)bh * TX_ + qbase + quad * 4 + r;
            pacc[((size_t)split * R + gr) * 64 + t * 16 + m16] = o[t][r];
        }
    if (m16 == 0) {
#pragma unroll
        for (int r = 0; r < 4; r++) {
            const size_t gr = (size_t)bh * TX_ + qbase + quad * 4 + r;
            pml[((size_t)split * R + gr) * 2 + 0] = m[r];
            pml[((size_t)split * R + gr) * 2 + 1] = l[r];
        }
    }
}

// ---------------------------------------------------------------------------
// Combine NSPLIT partials -> Ob bf16 (B,TX,C)
// ---------------------------------------------------------------------------
__global__ __launch_bounds__(256)
void combine_kernel(const float* __restrict__ pacc,
                    const float* __restrict__ pml,
                    __bf16* __restrict__ O)
{
    const int d   = threadIdx.x;
    const int sub = threadIdx.y;
    const size_t R = (size_t)B_ * H_ * TX_;
    const size_t r = (size_t)blockIdx.x * 4 + sub;
    const int bh  = (int)(r / TX_);
    const int txg = (int)(r % TX_);
    const int b = bh / H_, h = bh % H_;

    float mv[NSPLIT], lv[NSPLIT];
    float M = -INFINITY;
#pragma unroll
    for (int s = 0; s < NSPLIT; s++) {
        mv[s] = pml[((size_t)s * R + r) * 2 + 0];
        lv[s] = pml[((size_t)s * R + r) * 2 + 1];
        if (lv[s] > 0.f) M = fmaxf(M, mv[s]);
    }
    float L = 0.f, val = 0.f;
#pragma unroll
    for (int s = 0; s < NSPLIT; s++) {
        if (lv[s] > 0.f) {
            const float w = __expf(mv[s] - M);
            L += lv[s] * w;
            val += pacc[((size_t)s * R + r) * 64 + d] * w;
        }
    }
    const float o = (L > 0.f) ? val / L : 0.f;
    O[(size_t)(b * TX_ + txg) * C_ + h * D_ + d] = (__bf16)o;
}

// ---------------------------------------------------------------------------
extern "C" void kernel_launch(void* const* d_in, const int* in_sizes, int n_in,
                              void* d_out, int out_size, void* d_ws, size_t ws_size,
                              hipStream_t stream)
{
    const float* x        = (const float*)d_in[0];
    const float* x_t      = (const float*)d_in[1];
    const float* y        = (const float*)d_in[2];
    const float* y_t      = (const float*)d_in[3];
    const int*   dist     = (const int*)d_in[4];
    const int*   min_dist = (const int*)d_in[5];
    const float* Wq       = (const float*)d_in[6];
    const float* Wkv      = (const float*)d_in[7];
    const float* Wproj    = (const float*)d_in[8];
    const float* inv_freq = (const float*)d_in[9];
    float* out = (float*)d_out;

    const size_t QN = (size_t)B_ * TX_ * C_;
    const size_t KN = (size_t)B_ * TY_ * C_;
    const size_t R  = (size_t)B_ * H_ * TX_;

    float* ws = (float*)d_ws;
    float* pacc = ws; ws += (size_t)NSPLIT * R * 64;
    float* pml  = ws; ws += (size_t)NSPLIT * R * 2;
    __bf16* bws = (__bf16*)ws;
    __bf16* xb    = bws; bws += QN;
    __bf16* yb    = bws; bws += KN;
    __bf16* Wqt   = bws; bws += (size_t)C_ * C_;
    __bf16* Wkvt  = bws; bws += (size_t)C_ * 2 * C_;
    __bf16* Wprt  = bws; bws += (size_t)C_ * C_;
    __bf16* Ob    = bws; bws += QN;
    __bf16* Qbh   = bws; bws += QN;   // [bh][TX][64]
    __bf16* Kbh   = bws; bws += KN;   // [bh][TY][64]
    __bf16* Vtb   = bws; bws += KN;   // [bh][64][TY]

    conv_bf16<<<dim3((unsigned)(QN / 1024)), dim3(256), 0, stream>>>(x, xb, (int)QN);
    conv_bf16<<<dim3((unsigned)(KN / 1024)), dim3(256), 0, stream>>>(y, yb, (int)KN);
    transp_bf16<<<dim3(C_ / 32, C_ / 32), dim3(32, 8), 0, stream>>>(Wq, Wqt, C_, C_, 0.125f);
    transp_bf16<<<dim3(2 * C_ / 32, C_ / 32), dim3(32, 8), 0, stream>>>(Wkv, Wkvt, C_, 2 * C_, 1.0f);
    transp_bf16<<<dim3(C_ / 32, C_ / 32), dim3(32, 8), 0, stream>>>(Wproj, Wprt, C_, C_, 1.0f);

    mfma_gemm<1><<<dim3(C_ / 128, (B_ * TX_) / 128), dim3(256), 0, stream>>>(
        xb, Wqt, nullptr, Qbh, nullptr, x_t, inv_freq, C_);
    mfma_gemm<2><<<dim3(2 * C_ / 128, (B_ * TY_) / 128), dim3(256), 0, stream>>>(
        yb, Wkvt, nullptr, Kbh, Vtb, y_t, inv_freq, 2 * C_);
    attn_mfma<<<dim3(TX_ / 64, B_ * H_, NSPLIT), dim3(256), 0, stream>>>(
        Qbh, Kbh, Vtb, x_t, y_t, dist, min_dist, pacc, pml);
    combine_kernel<<<dim3((unsigned)(R / 4)), dim3(64, 4), 0, stream>>>(
        pacc, pml, Ob);
    mfma_gemm<0><<<dim3(C_ / 128, (B_ * TX_) / 128), dim3(256), 0, stream>>>(
        Ob, Wprt, out, nullptr, nullptr, nullptr, nullptr, C_);
}

// Round 6
// 212.190 us; speedup vs baseline: 3.2511x; 1.1560x over previous
//
#include <hip/hip_runtime.h>
#include <hip/hip_bf16.h>
#include <math.h>

#define B_ 2
#define TX_ 1024
#define TY_ 4096
#define C_ 768
#define H_ 12
#define D_ 64
#define NSPLIT 4

typedef __bf16 bf16x8 __attribute__((ext_vector_type(8)));
typedef float floatx4 __attribute__((ext_vector_type(4)));

__device__ __forceinline__ void async_copy16(const void* g, void* l) {
    __builtin_amdgcn_global_load_lds(
        (const __attribute__((address_space(1))) unsigned int*)g,
        (__attribute__((address_space(3))) unsigned int*)l,
        16, 0, 0);
}

__device__ __forceinline__ bf16x8 cvt8(const float* s) {
    bf16x8 r;
#pragma unroll
    for (int i = 0; i < 8; i++) r[i] = (__bf16)s[i];
    return r;
}

// ---------------------------------------------------------------------------
// fused f32 -> bf16 convert for x and y
// ---------------------------------------------------------------------------
__global__ __launch_bounds__(256)
void conv2_bf16(const float* __restrict__ x, __bf16* __restrict__ xb, int nx,
                const float* __restrict__ y, __bf16* __restrict__ yb, int ny)
{
    int i = (blockIdx.x * 256 + threadIdx.x) * 4;
    const float* src; __bf16* dst; int j;
    if (i < nx) { src = x; dst = xb; j = i; }
    else        { src = y; dst = yb; j = i - nx; if (j >= ny) return; }
    float4 v = *(const float4*)(src + j);
    union { __bf16 h[4]; uint2 u; } p;
    p.h[0] = (__bf16)v.x; p.h[1] = (__bf16)v.y;
    p.h[2] = (__bf16)v.z; p.h[3] = (__bf16)v.w;
    *(uint2*)(dst + j) = p.u;
}

// ---------------------------------------------------------------------------
// fused transpose of all 3 weights: W(768 x N f32) -> Wt(N x 768 bf16)
// blockIdx.x: [0,24) Wq | [24,72) Wkv | [72,96) Wproj
// ---------------------------------------------------------------------------
__global__ __launch_bounds__(256)
void transp_all(const float* __restrict__ Wq,   __bf16* __restrict__ Wqt,
                const float* __restrict__ Wkv,  __bf16* __restrict__ Wkvt,
                const float* __restrict__ Wpr,  __bf16* __restrict__ Wprt)
{
    __shared__ float tile[32][33];
    const int bxr = blockIdx.x;
    const float* W; __bf16* Wt; int N, nb; float scale = 1.0f;
    if (bxr < 24)      { W = Wq;  Wt = Wqt;  N = C_;     nb = bxr;      scale = 0.125f; }
    else if (bxr < 72) { W = Wkv; Wt = Wkvt; N = 2 * C_; nb = bxr - 24; }
    else               { W = Wpr; Wt = Wprt; N = C_;     nb = bxr - 72; }
    const int bx = nb * 32;
    const int by = blockIdx.y * 32;
    const int tx = threadIdx.x & 31, ty = threadIdx.x >> 5;
#pragma unroll
    for (int i = 0; i < 4; i++)
        tile[ty + i * 8][tx] = W[(size_t)(by + ty + i * 8) * N + bx + tx];
    __syncthreads();
#pragma unroll
    for (int i = 0; i < 4; i++)
        Wt[(size_t)(bx + ty + i * 8) * C_ + by + tx] =
            (__bf16)(tile[tx][ty + i * 8] * scale);
}

// ---------------------------------------------------------------------------
// Fused Q + KV MFMA GEMM. 128x128 tile, BK=32, 2x2 waves.
// blockIdx.y < 64 : KV rows (A=yb, Bt=Wkvt, N=1536): n0<C_ -> roped K
//   head-major bf16 [bh][TY][64]; n0>=C_ -> V transposed bf16 [bh][64][TY].
// blockIdx.y >= 64: Q rows (A=xb, Bt=Wqt, N=768, bx<6): roped Q head-major
//   bf16 [bh][TX][64].
// ---------------------------------------------------------------------------
__global__ __launch_bounds__(256)
void gemm_qkv(const __bf16* __restrict__ xb, const __bf16* __restrict__ Wqt,
              const __bf16* __restrict__ yb, const __bf16* __restrict__ Wkvt,
              __bf16* __restrict__ Qbh, __bf16* __restrict__ Kbh,
              __bf16* __restrict__ Vtb,
              const float* __restrict__ x_t, const float* __restrict__ y_t,
              const float* __restrict__ inv_freq)
{
    const bool isQ = (blockIdx.y >= 64);
    if (isQ && blockIdx.x >= 6) return;

    const __bf16* A; const __bf16* Bt; const float* t_arr;
    int row0, T, TSH;
    if (isQ) { A = xb; Bt = Wqt;  t_arr = x_t; row0 = (blockIdx.y - 64) * 128; T = TX_; TSH = 10; }
    else     { A = yb; Bt = Wkvt; t_arr = y_t; row0 = blockIdx.y * 128;        T = TY_; TSH = 12; }
    const int n0 = blockIdx.x * 128;
    const bool isV = (!isQ) && (n0 >= C_);

    __shared__ __align__(16) float smem_f[4224];   // 16896 B
    __bf16* As = (__bf16*)smem_f;

    const int tid  = threadIdx.x;
    const int wave = tid >> 6;
    const int lane = tid & 63;
    const int m16  = lane & 15;
    const int quad = lane >> 4;
    const int wm   = wave >> 1;
    const int wn   = wave & 1;

    floatx4 acc[4][4];
#pragma unroll
    for (int i = 0; i < 4; i++)
#pragma unroll
        for (int j = 0; j < 4; j++) acc[i][j] = (floatx4){0.f, 0.f, 0.f, 0.f};

    int srow[4], scol[4];
#pragma unroll
    for (int j = 0; j < 4; j++) {
        int e = j * 2048 + wave * 512 + lane * 8;
        int e2 = e & 4095;
        srow[j] = e2 >> 5;
        scol[j] = e2 & 31;
    }

    for (int k0 = 0; k0 < C_; k0 += 32) {
        __syncthreads();
#pragma unroll
        for (int j = 0; j < 4; j++) {
            const __bf16* src = (j < 2)
                ? A  + (size_t)(row0 + srow[j]) * C_ + (k0 + scol[j])
                : Bt + (size_t)(n0   + srow[j]) * C_ + (k0 + scol[j]);
            async_copy16(src, (char*)smem_f + j * 4096 + wave * 1024);
        }
        __syncthreads();

        bf16x8 af[4], bfr[4];
#pragma unroll
        for (int i = 0; i < 4; i++)
            af[i] = *(const bf16x8*)(As + (size_t)(wm * 64 + i * 16 + m16) * 32 + quad * 8);
#pragma unroll
        for (int j = 0; j < 4; j++)
            bfr[j] = *(const bf16x8*)(As + 4096 + (size_t)(wn * 64 + j * 16 + m16) * 32 + quad * 8);
#pragma unroll
        for (int i = 0; i < 4; i++)
#pragma unroll
            for (int j = 0; j < 4; j++)
                acc[i][j] = __builtin_amdgcn_mfma_f32_16x16x32_bf16(af[i], bfr[j], acc[i][j], 0, 0, 0);
    }

    // ---- epilogue (LDS-staged) ----
    const int STR = 132;
    float* fs = smem_f;

#pragma unroll
    for (int i = 0; i < 4; i++) {
        __syncthreads();
#pragma unroll
        for (int j = 0; j < 4; j++) {
            const int col_l = wn * 64 + j * 16 + m16;
#pragma unroll
            for (int r = 0; r < 4; r++) {
                const int row_l = quad * 4 + r;
                float v = acc[i][j][r];
                if (!isV) {
                    const float vp = __shfl_xor(v, 1);
                    const int row = row0 + wm * 64 + i * 16 + row_l;
                    const int cc = (n0 + col_l) & (D_ - 1);
                    const float fr = t_arr[row] * inv_freq[cc >> 1];
                    const float sn = __sinf(fr), cs = __cosf(fr);
                    v = (m16 & 1) ? (v * cs + vp * sn) : (v * cs - vp * sn);
                }
                fs[(wm * 16 + row_l) * STR + col_l] = v;
            }
        }
        __syncthreads();

        if (!isV) {
            // bf16 head-major [bh][T][64]
            __bf16* outb = isQ ? Qbh : Kbh;
            const int r32 = tid >> 3;
            const int lane8 = tid & 7;
            const int grow = row0 + (r32 >> 4) * 64 + i * 16 + (r32 & 15);
            const int bb = grow >> TSH;
            const int rk = grow & (T - 1);
            const int h  = (n0 >> 6) + (lane8 >> 2);
            const int d0 = (lane8 & 3) * 16;
            __bf16* gp = outb + ((size_t)(bb * H_ + h) * T + rk) * 64 + d0;
            const float* sp = &fs[r32 * STR + lane8 * 16];
            *(bf16x8*)gp       = cvt8(sp);
            *(bf16x8*)(gp + 8) = cvt8(sp + 8);
        } else {
            // V transposed bf16 [bh][64][TY]
            const int dcol = tid >> 1;
            const int g16  = tid & 1;
            const int h  = ((n0 - C_) >> 6) + (dcol >> 6);
            const int dd = dcol & 63;
            const int kbase = row0 + g16 * 64 + i * 16;
            const int bb  = kbase >> 12;
            const int kin = kbase & (TY_ - 1);
            float tmp[16];
#pragma unroll
            for (int jj = 0; jj < 16; jj++)
                tmp[jj] = fs[(g16 * 16 + jj) * STR + dcol];
            __bf16* gp = Vtb + ((size_t)(bb * H_ + h) * 64 + dd) * TY_ + kin;
            *(bf16x8*)gp       = cvt8(tmp);
            *(bf16x8*)(gp + 8) = cvt8(tmp + 8);
        }
    }
}

// ---------------------------------------------------------------------------
// MFMA flash attention, NO-MAX softmax (scores are O(1): exp is safe, and
// softmax is shift-invariant). Block = 4 waves = 64 q rows; chunk = 32 k.
// ---------------------------------------------------------------------------
__global__ __launch_bounds__(256)
void attn_mfma(const __bf16* __restrict__ Qb,
               const __bf16* __restrict__ Kb,
               const __bf16* __restrict__ Vt,
               const float* __restrict__ x_t,
               const float* __restrict__ y_t,
               const int* __restrict__ dist_p,
               const int* __restrict__ min_dist_p,
               float* __restrict__ pacc,
               float* __restrict__ pml)
{
    __shared__ __align__(16) __bf16 Kc[32 * 64];   // [k][d]
    __shared__ __align__(16) __bf16 Vc[64 * 32];   // [d][k]
    __shared__ __align__(16) __bf16 Pt[4][16 * 32];

    const int tid  = threadIdx.x;
    const int wave = tid >> 6;
    const int m16  = tid & 15;
    const int quad = (tid & 63) >> 4;
    const int qt = blockIdx.x, bh = blockIdx.y, split = blockIdx.z;
    const int b = bh / H_;
    const int qblk  = qt * 64;
    const int qbase = qblk + wave * 16;

    const float dist = (float)dist_p[0];
    const float md   = (float)min_dist_p[0];
    const float* yt = y_t + (size_t)b * TY_;
    const float* xt = x_t + (size_t)b * TX_;

    // block k-window (union over 64 sorted q rows)
    const float xtmin = xt[qblk] - md;
    const float xtmax = xt[qblk + 63] - md;
    int lo = 0, hi = TY_;
    while (lo < hi) { int mid = (lo + hi) >> 1; if (yt[mid] + dist < xtmin) lo = mid + 1; else hi = mid; }
    const int klo = lo;
    lo = 0; hi = TY_;
    while (lo < hi) { int mid = (lo + hi) >> 1; if (yt[mid] <= xtmax) lo = mid + 1; else hi = mid; }
    const int khi = lo - 1;
    const int len = khi - klo + 1;

    int k0 = klo, k1 = klo;
    if (len > 0) {
        const int cnt = (len + NSPLIT - 1) / NSPLIT;
        k0 = klo + split * cnt;
        k1 = min(k0 + cnt, klo + len);
    }

    float xtq[4];
#pragma unroll
    for (int r = 0; r < 4; r++)
        xtq[r] = xt[qbase + quad * 4 + r] - md;

    const __bf16* qp = Qb + ((size_t)bh * TX_ + qbase + m16) * 64;
    const bf16x8 aq0 = *(const bf16x8*)(qp + quad * 8);
    const bf16x8 aq1 = *(const bf16x8*)(qp + 32 + quad * 8);

    float l[4];
    floatx4 o[4];
#pragma unroll
    for (int r = 0; r < 4; r++) l[r] = 0.f;
#pragma unroll
    for (int t = 0; t < 4; t++) o[t] = (floatx4){0.f, 0.f, 0.f, 0.f};

    for (int kc = k0; kc < k1; kc += 32) {
        const float yt0 = yt[min(kc + m16, TY_ - 1)];
        const float yt1 = yt[min(kc + 16 + m16, TY_ - 1)];

        __syncthreads();
        {
            const int krow = tid >> 3;
            const int kg = min(kc + krow, TY_ - 1);
            async_copy16(Kb + ((size_t)bh * TY_ + kg) * 64 + (tid & 7) * 8,
                         (char*)Kc + tid * 16);
            const int d = tid >> 2;
            const int kv = min(kc + (tid & 3) * 8, TY_ - 8);
            async_copy16(Vt + ((size_t)bh * 64 + d) * TY_ + kv,
                         (char*)Vc + tid * 16);
        }
        __syncthreads();

        // QK^T: S[16q x 32k] as two 16-col halves
        const bf16x8 bk0h0 = *(const bf16x8*)(Kc + m16 * 64 + quad * 8);
        const bf16x8 bk1h0 = *(const bf16x8*)(Kc + m16 * 64 + 32 + quad * 8);
        const bf16x8 bk0h1 = *(const bf16x8*)(Kc + (16 + m16) * 64 + quad * 8);
        const bf16x8 bk1h1 = *(const bf16x8*)(Kc + (16 + m16) * 64 + 32 + quad * 8);
        floatx4 s0 = (floatx4){0.f, 0.f, 0.f, 0.f};
        floatx4 s1 = (floatx4){0.f, 0.f, 0.f, 0.f};
        s0 = __builtin_amdgcn_mfma_f32_16x16x32_bf16(aq0, bk0h0, s0, 0, 0, 0);
        s0 = __builtin_amdgcn_mfma_f32_16x16x32_bf16(aq1, bk1h0, s0, 0, 0, 0);
        s1 = __builtin_amdgcn_mfma_f32_16x16x32_bf16(aq0, bk0h1, s1, 0, 0, 0);
        s1 = __builtin_amdgcn_mfma_f32_16x16x32_bf16(aq1, bk1h1, s1, 0, 0, 0);

        const int kg0 = kc + m16;
        const int kg1 = kc + 16 + m16;
        __bf16* pt = Pt[wave];
#pragma unroll
        for (int r = 0; r < 4; r++) {
            const bool v0 = (kg0 < k1) && (xtq[r] >= yt0) && (xtq[r] <= yt0 + dist);
            const bool v1 = (kg1 < k1) && (xtq[r] >= yt1) && (xtq[r] <= yt1 + dist);
            const float p0 = v0 ? (float)(__bf16)__expf(s0[r]) : 0.f;
            const float p1 = v1 ? (float)(__bf16)__expf(s1[r]) : 0.f;
            l[r] += p0 + p1;
            pt[(quad * 4 + r) * 32 + m16]      = (__bf16)p0;
            pt[(quad * 4 + r) * 32 + 16 + m16] = (__bf16)p1;
        }
        const bf16x8 ap = *(const bf16x8*)(pt + m16 * 32 + quad * 8);
#pragma unroll
        for (int t = 0; t < 4; t++) {
            const bf16x8 bv = *(const bf16x8*)(Vc + (t * 16 + m16) * 32 + quad * 8);
            o[t] = __builtin_amdgcn_mfma_f32_16x16x32_bf16(ap, bv, o[t], 0, 0, 0);
        }
    }

    // final lane-sum of l over the 16 columns
#pragma unroll
    for (int r = 0; r < 4; r++) {
#pragma unroll
        for (int w = 1; w < 16; w <<= 1)
            l[r] += __shfl_xor(l[r], w);
    }

    const size_t R = (size_t)B_ * H_ * TX_;
#pragma unroll
    for (int t = 0; t < 4; t++)
#pragma unroll
        for (int r = 0; r < 4; r++) {
            const size_t gr = (size_t)bh * TX_ + qbase + quad * 4 + r;
            pacc[((size_t)split * R + gr) * 64 + t * 16 + m16] = o[t][r];
        }
    if (m16 == 0) {
#pragma unroll
        for (int r = 0; r < 4; r++) {
            const size_t gr = (size_t)bh * TX_ + qbase + quad * 4 + r;
            pml[(size_t)split * R + gr] = l[r];
        }
    }
}

// ---------------------------------------------------------------------------
// Combine NSPLIT partials (all share m=0) -> Ob bf16 (B,TX,C)
// ---------------------------------------------------------------------------
__global__ __launch_bounds__(256)
void combine_kernel(const float* __restrict__ pacc,
                    const float* __restrict__ pml,
                    __bf16* __restrict__ O)
{
    const int d   = threadIdx.x;
    const int sub = threadIdx.y;
    const size_t R = (size_t)B_ * H_ * TX_;
    const size_t r = (size_t)blockIdx.x * 4 + sub;
    const int bh  = (int)(r / TX_);
    const int txg = (int)(r % TX_);
    const int b = bh / H_, h = bh % H_;

    float L = 0.f, val = 0.f;
#pragma unroll
    for (int s = 0; s < NSPLIT; s++) {
        L   += pml[(size_t)s * R + r];
        val += pacc[((size_t)s * R + r) * 64 + d];
    }
    const float o = (L > 0.f) ? val / L : 0.f;
    O[(size_t)(b * TX_ + txg) * C_ + h * D_ + d] = (__bf16)o;
}

// ---------------------------------------------------------------------------
// proj GEMM: out(M,768 f32) = A(M,768 bf16) @ Bt(768,768 bf16)^T
// ---------------------------------------------------------------------------
__global__ __launch_bounds__(256)
void gemm_proj(const __bf16* __restrict__ A,
               const __bf16* __restrict__ Bt,
               float* __restrict__ out0)
{
    __shared__ __align__(16) float smem_f[4224];
    __bf16* As = (__bf16*)smem_f;

    const int tid  = threadIdx.x;
    const int wave = tid >> 6;
    const int lane = tid & 63;
    const int m16  = lane & 15;
    const int quad = lane >> 4;
    const int wm   = wave >> 1;
    const int wn   = wave & 1;
    const int row0 = blockIdx.y * 128;
    const int n0   = blockIdx.x * 128;

    floatx4 acc[4][4];
#pragma unroll
    for (int i = 0; i < 4; i++)
#pragma unroll
        for (int j = 0; j < 4; j++) acc[i][j] = (floatx4){0.f, 0.f, 0.f, 0.f};

    int srow[4], scol[4];
#pragma unroll
    for (int j = 0; j < 4; j++) {
        int e = j * 2048 + wave * 512 + lane * 8;
        int e2 = e & 4095;
        srow[j] = e2 >> 5;
        scol[j] = e2 & 31;
    }

    for (int k0 = 0; k0 < C_; k0 += 32) {
        __syncthreads();
#pragma unroll
        for (int j = 0; j < 4; j++) {
            const __bf16* src = (j < 2)
                ? A  + (size_t)(row0 + srow[j]) * C_ + (k0 + scol[j])
                : Bt + (size_t)(n0   + srow[j]) * C_ + (k0 + scol[j]);
            async_copy16(src, (char*)smem_f + j * 4096 + wave * 1024);
        }
        __syncthreads();

        bf16x8 af[4], bfr[4];
#pragma unroll
        for (int i = 0; i < 4; i++)
            af[i] = *(const bf16x8*)(As + (size_t)(wm * 64 + i * 16 + m16) * 32 + quad * 8);
#pragma unroll
        for (int j = 0; j < 4; j++)
            bfr[j] = *(const bf16x8*)(As + 4096 + (size_t)(wn * 64 + j * 16 + m16) * 32 + quad * 8);
#pragma unroll
        for (int i = 0; i < 4; i++)
#pragma unroll
            for (int j = 0; j < 4; j++)
                acc[i][j] = __builtin_amdgcn_mfma_f32_16x16x32_bf16(af[i], bfr[j], acc[i][j], 0, 0, 0);
    }

    const int STR = 132;
    float* fs = smem_f;
#pragma unroll
    for (int i = 0; i < 4; i++) {
        __syncthreads();
#pragma unroll
        for (int j = 0; j < 4; j++) {
            const int col_l = wn * 64 + j * 16 + m16;
#pragma unroll
            for (int r = 0; r < 4; r++)
                fs[(wm * 16 + quad * 4 + r) * STR + col_l] = acc[i][j][r];
        }
        __syncthreads();
        const int r32 = tid >> 3;
        const int lc  = (tid & 7) * 4;
        const int row = row0 + (r32 >> 4) * 64 + i * 16 + (r32 & 15);
        float* gp = out0 + (size_t)row * C_ + n0;
#pragma unroll
        for (int c2 = 0; c2 < 4; c2++) {
            float4 v4 = *(const float4*)&fs[r32 * STR + c2 * 32 + lc];
            *(float4*)(gp + c2 * 32 + lc) = v4;
        }
    }
}

// ---------------------------------------------------------------------------
extern "C" void kernel_launch(void* const* d_in, const int* in_sizes, int n_in,
                              void* d_out, int out_size, void* d_ws, size_t ws_size,
                              hipStream_t stream)
{
    const float* x        = (const float*)d_in[0];
    const float* x_t      = (const float*)d_in[1];
    const float* y        = (const float*)d_in[2];
    const float* y_t      = (const float*)d_in[3];
    const int*   dist     = (const int*)d_in[4];
    const int*   min_dist = (const int*)d_in[5];
    const float* Wq       = (const float*)d_in[6];
    const float* Wkv      = (const float*)d_in[7];
    const float* Wproj    = (const float*)d_in[8];
    const float* inv_freq = (const float*)d_in[9];
    float* out = (float*)d_out;

    const size_t QN = (size_t)B_ * TX_ * C_;
    const size_t KN = (size_t)B_ * TY_ * C_;
    const size_t R  = (size_t)B_ * H_ * TX_;

    float* ws = (float*)d_ws;
    float* pacc = ws; ws += (size_t)NSPLIT * R * 64;
    float* pml  = ws; ws += (size_t)NSPLIT * R;
    __bf16* bws = (__bf16*)ws;
    __bf16* xb    = bws; bws += QN;
    __bf16* yb    = bws; bws += KN;
    __bf16* Wqt   = bws; bws += (size_t)C_ * C_;
    __bf16* Wkvt  = bws; bws += (size_t)C_ * 2 * C_;
    __bf16* Wprt  = bws; bws += (size_t)C_ * C_;
    __bf16* Ob    = bws; bws += QN;
    __bf16* Qbh   = bws; bws += QN;   // [bh][TX][64]
    __bf16* Kbh   = bws; bws += KN;   // [bh][TY][64]
    __bf16* Vtb   = bws; bws += KN;   // [bh][64][TY]

    conv2_bf16<<<dim3((unsigned)((QN + KN) / 1024)), dim3(256), 0, stream>>>(
        x, xb, (int)QN, y, yb, (int)KN);
    transp_all<<<dim3(96, 24), dim3(256), 0, stream>>>(
        Wq, Wqt, Wkv, Wkvt, Wproj, Wprt);

    // fused Q + KV GEMM (y: 0..63 KV row tiles, 64..79 Q row tiles)
    gemm_qkv<<<dim3(12, 80), dim3(256), 0, stream>>>(
        xb, Wqt, yb, Wkvt, Qbh, Kbh, Vtb, x_t, y_t, inv_freq);

    attn_mfma<<<dim3(TX_ / 64, B_ * H_, NSPLIT), dim3(256), 0, stream>>>(
        Qbh, Kbh, Vtb, x_t, y_t, dist, min_dist, pacc, pml);
    combine_kernel<<<dim3((unsigned)(R / 4)), dim3(64, 4), 0, stream>>>(
        pacc, pml, Ob);
    gemm_proj<<<dim3(C_ / 128, (B_ * TX_) / 128), dim3(256), 0, stream>>>(
        Ob, Wprt, out);
}